// Round 2
// baseline (1028.626 us; speedup 1.0000x reference)
//
#include <hip/hip_runtime.h>
#include <hip/hip_bf16.h>
#include <stdint.h>

#define N_ROWS 16384
#define E_DIM 512
#define C_DIM 128
#define K_CODES 2048
#define M_BOOKS 4
#define H1_DIM 128
#define H2_DIM 256
#define EPS_V 1e-5f

// ---- fused GEMM: C = act(A[N,Kd] @ B[Kd,Hc] + bias), optional BN+ReLU ----
// blockIdx.z strides A/B/params/outputs for batched (per-book) use.
template<bool BNRELU>
__global__ __launch_bounds__(256) void gemm_fused(
    const float* __restrict__ A, const float* __restrict__ B,
    const float* __restrict__ bias, const float* __restrict__ bn_g,
    const float* __restrict__ bn_b, const float* __restrict__ bn_m,
    const float* __restrict__ bn_v, float* __restrict__ C,
    int Kd, int Hc, size_t sA, size_t sB, size_t sP, size_t sC)
{
    const int BK = 16;
    __shared__ float As[BK][64];
    __shared__ float Bs[BK][64];
    const int z = blockIdx.z;
    A += (size_t)z * sA;
    B += (size_t)z * sB;
    bias += (size_t)z * sP;
    if (BNRELU) {
        bn_g += (size_t)z * sP; bn_b += (size_t)z * sP;
        bn_m += (size_t)z * sP; bn_v += (size_t)z * sP;
    }

    const int t = threadIdx.x;
    const int tx = t & 15, ty = t >> 4;
    const int row0 = blockIdx.y * 64;
    const int col0 = blockIdx.x * 64;
    const int lr = t >> 2, lk = (t & 3) * 4;   // A-tile load coords (64 rows x 16 k)
    const int bk = t >> 4, bj = (t & 15) * 4;  // B-tile load coords (16 k x 64 cols)

    float acc[4][4] = {};
    for (int k0 = 0; k0 < Kd; k0 += BK) {
        float4 av = *(const float4*)(A + (size_t)(row0 + lr) * Kd + (k0 + lk));
        As[lk+0][lr] = av.x; As[lk+1][lr] = av.y; As[lk+2][lr] = av.z; As[lk+3][lr] = av.w;
        float4 bv = *(const float4*)(B + (size_t)(k0 + bk) * Hc + (col0 + bj));
        *(float4*)&Bs[bk][bj] = bv;
        __syncthreads();
        #pragma unroll
        for (int kk = 0; kk < BK; ++kk) {
            float4 a4 = *(const float4*)&As[kk][ty*4];
            float4 b4 = *(const float4*)&Bs[kk][tx*4];
            float a[4] = {a4.x, a4.y, a4.z, a4.w};
            float b[4] = {b4.x, b4.y, b4.z, b4.w};
            #pragma unroll
            for (int i = 0; i < 4; ++i)
                #pragma unroll
                for (int j = 0; j < 4; ++j)
                    acc[i][j] = fmaf(a[i], b[j], acc[i][j]);
        }
        __syncthreads();
    }

    #pragma unroll
    for (int j = 0; j < 4; ++j) {
        const int col = col0 + tx*4 + j;
        const float bi = bias[col];
        float sc = 0.f, mu = 0.f, be = 0.f;
        if (BNRELU) {
            sc = bn_g[col] / sqrtf(bn_v[col] + EPS_V);  // matches g / sqrt(v+eps)
            mu = bn_m[col]; be = bn_b[col];
        }
        #pragma unroll
        for (int i = 0; i < 4; ++i) {
            const int row = row0 + ty*4 + i;
            float v = acc[i][j] + bi;
            if (BNRELU) {
                float p = (v - mu) * sc;
                asm volatile("" : "+v"(p));   // block fma contraction (numpy rounds separately)
                v = fmaxf(p + be, 0.0f);
            }
            C[(size_t)z * sC + (size_t)row * Hc + col] = v;
        }
    }
}

// ---- row-wise sum of squares, emulating numpy's 8-accumulator pairwise sum ----
__global__ __launch_bounds__(256) void rowsq_np(const float* __restrict__ X,
                                                float* __restrict__ out, int rows)
{
    const int r = blockIdx.x * blockDim.x + threadIdx.x;
    if (r >= rows) return;
    const float* p = X + (size_t)r * C_DIM;
    float rr[8];
    #pragma unroll
    for (int j = 0; j < 8; ++j) {
        float v = p[j]; float s2 = v * v;
        asm volatile("" : "+v"(s2));
        rr[j] = s2;
    }
    for (int i = 8; i < C_DIM; i += 8) {
        #pragma unroll
        for (int j = 0; j < 8; ++j) {
            float v = p[i + j]; float s2 = v * v;
            asm volatile("" : "+v"(s2));    // keep mul+add separate (no fma), like np
            rr[j] = rr[j] + s2;
        }
    }
    out[r] = ((rr[0]+rr[1]) + (rr[2]+rr[3])) + ((rr[4]+rr[5]) + (rr[6]+rr[7]));
}

// ---- VQ: cross GEMM (ze @ cb^T) fused with argmin; merge via u64 atomicMin ----
__global__ __launch_bounds__(256) void vq_argmin(
    const float* __restrict__ ze, const float* __restrict__ cb,
    const float* __restrict__ ze_sq, const float* __restrict__ cb_sq,
    unsigned long long* __restrict__ keys)
{
    const int BK = 16;
    __shared__ float As[BK][64];
    __shared__ float Bs[BK][64];
    __shared__ float rd[4][16][16];
    __shared__ int   ri[4][16][16];

    const int m = blockIdx.z;
    const float* Zm  = ze + (size_t)m * N_ROWS * C_DIM;
    const float* Bm  = cb + (size_t)m * K_CODES * C_DIM;
    const float* zsm = ze_sq + (size_t)m * N_ROWS;
    const float* csm = cb_sq + (size_t)m * K_CODES;

    const int t = threadIdx.x;
    const int tx = t & 15, ty = t >> 4;
    const int row0 = blockIdx.y * 64;
    const int col0 = blockIdx.x * 64;
    const int lr = t >> 2, lk = (t & 3) * 4;

    float acc[4][4] = {};
    for (int k0 = 0; k0 < C_DIM; k0 += BK) {
        float4 av = *(const float4*)(Zm + (size_t)(row0 + lr) * C_DIM + (k0 + lk));
        As[lk+0][lr] = av.x; As[lk+1][lr] = av.y; As[lk+2][lr] = av.z; As[lk+3][lr] = av.w;
        float4 bv = *(const float4*)(Bm + (size_t)(col0 + lr) * C_DIM + (k0 + lk));
        Bs[lk+0][lr] = bv.x; Bs[lk+1][lr] = bv.y; Bs[lk+2][lr] = bv.z; Bs[lk+3][lr] = bv.w;
        __syncthreads();
        #pragma unroll
        for (int kk = 0; kk < BK; ++kk) {
            float4 a4 = *(const float4*)&As[kk][ty*4];
            float4 b4 = *(const float4*)&Bs[kk][tx*4];
            float a[4] = {a4.x, a4.y, a4.z, a4.w};
            float b[4] = {b4.x, b4.y, b4.z, b4.w};
            #pragma unroll
            for (int i = 0; i < 4; ++i)
                #pragma unroll
                for (int j = 0; j < 4; ++j)
                    acc[i][j] = fmaf(a[i], b[j], acc[i][j]);
        }
        __syncthreads();
    }

    #pragma unroll
    for (int i = 0; i < 4; ++i) {
        const int row = row0 + ty*4 + i;
        const float zs = zsm[row];
        float bd = 3.4e38f; int bc = 0;
        #pragma unroll
        for (int j = 0; j < 4; ++j) {
            const int code = col0 + tx*4 + j;
            // reference order: (ze_sq + cb_sq) - 2*cross  (2*acc is exact)
            const float d = (zs + csm[code]) - 2.0f * acc[i][j];
            if (d < bd) { bd = d; bc = code; }   // strict < -> first (smallest) index on ties
        }
        rd[i][ty][tx] = bd; ri[i][ty][tx] = bc;
    }
    __syncthreads();
    if (t < 64) {
        const int i = t & 3, yy = t >> 2;
        float bd = rd[i][yy][0]; int bc = ri[i][yy][0];
        #pragma unroll
        for (int k2 = 1; k2 < 16; ++k2) {
            const float d = rd[i][yy][k2];
            if (d < bd) { bd = d; bc = ri[i][yy][k2]; }   // ascending code order
        }
        unsigned int ub = __float_as_uint(bd);
        ub = (ub & 0x80000000u) ? ~ub : (ub | 0x80000000u);  // monotone float->uint
        const unsigned long long key = ((unsigned long long)ub << 32) | (unsigned int)bc;
        const int row = row0 + yy*4 + i;
        atomicMin(&keys[(size_t)m * N_ROWS + row], key);     // ties -> smaller idx wins
    }
}

// ---- gather chosen codes: ce (fp32 out) + zq = sum_m ce ----
__global__ __launch_bounds__(256) void gather_ce_zq(
    const unsigned long long* __restrict__ keys, const float* __restrict__ cb,
    float* __restrict__ ce_out, float* __restrict__ zq)
{
    const int gid = blockIdx.x * 256 + threadIdx.x;
    const int n = gid >> 7, c = gid & 127;
    float s = 0.0f;
    #pragma unroll
    for (int m = 0; m < M_BOOKS; ++m) {
        const int idx = (int)(keys[(size_t)m * N_ROWS + n] & 0xFFFFFFFFull);
        const float v = cb[((size_t)m * K_CODES + idx) * C_DIM + c];
        ce_out[((size_t)m * N_ROWS + n) * (size_t)C_DIM + c] = v;
        s += v;   // sequential over m, matches np.sum(axis=0) for M=4
    }
    zq[gid] = s;
}

extern "C" void kernel_launch(void* const* d_in, const int* in_sizes, int n_in,
                              void* d_out, int out_size, void* d_ws, size_t ws_size,
                              hipStream_t stream)
{
    const float* x   = (const float*)d_in[0];
    const float* eW1 = (const float*)d_in[1];
    const float* eb1 = (const float*)d_in[2];
    const float* g1  = (const float*)d_in[3];
    const float* b1  = (const float*)d_in[4];
    const float* m1  = (const float*)d_in[5];
    const float* v1  = (const float*)d_in[6];
    const float* eW2 = (const float*)d_in[7];
    const float* eb2 = (const float*)d_in[8];
    const float* g2  = (const float*)d_in[9];
    const float* b2  = (const float*)d_in[10];
    const float* m2  = (const float*)d_in[11];
    const float* v2  = (const float*)d_in[12];
    const float* eW3 = (const float*)d_in[13];
    const float* eb3 = (const float*)d_in[14];
    const float* cb  = (const float*)d_in[15];
    const float* dW1 = (const float*)d_in[16];
    const float* db1 = (const float*)d_in[17];
    const float* dg1 = (const float*)d_in[18];
    const float* dbb1= (const float*)d_in[19];
    const float* dm1 = (const float*)d_in[20];
    const float* dv1 = (const float*)d_in[21];
    const float* dW2 = (const float*)d_in[22];
    const float* db2 = (const float*)d_in[23];
    const float* dg2 = (const float*)d_in[24];
    const float* dbb2= (const float*)d_in[25];
    const float* dm2 = (const float*)d_in[26];
    const float* dv2 = (const float*)d_in[27];
    const float* dW3 = (const float*)d_in[28];
    const float* db3 = (const float*)d_in[29];

    // Outputs are FLOAT32 (reference returns fp32; out_npz 61MB > bf16 raw 50MB).
    float* out_xhat = (float*)d_out;
    float* out_ze   = out_xhat + (size_t)N_ROWS * E_DIM;          // [M,N,C]
    float* out_ce   = out_ze + (size_t)M_BOOKS * N_ROWS * C_DIM;  // [M,N,C]

    float* ws = (float*)d_ws;
    const size_t h1N1 = (size_t)N_ROWS * H1_DIM;           // 2097152
    const size_t h2N1 = (size_t)N_ROWS * H2_DIM;           // 4194304
    const size_t smallN = (size_t)M_BOOKS*N_ROWS + (size_t)M_BOOKS*K_CODES
                        + 2 + 2*(size_t)M_BOOKS*N_ROWS;
    const size_t fullFloats = (size_t)M_BOOKS*(h1N1 + h2N1) + smallN;
    const bool fullM = ws_size >= fullFloats * sizeof(float) + 256;

    size_t off = 0;
    float* h1 = ws; off += (fullM ? M_BOOKS : 1) * h1N1;
    float* h2 = ws + off; off += (fullM ? M_BOOKS : 1) * h2N1;
    float* zesq = ws + off; off += (size_t)M_BOOKS * N_ROWS;
    float* cbsq = ws + off; off += (size_t)M_BOOKS * K_CODES;
    off = (off + 1) & ~(size_t)1;
    unsigned long long* keys = (unsigned long long*)(ws + off);
    float* zq = h1;   // reuse after encoders finish (N*C <= h1 region)
    float* d1 = h2;   // N*H2 == h2N1
    float* d2 = h1;   // zq dead once decoder L1 done; N*H1 fits

    hipMemsetAsync((void*)keys, 0xFF, (size_t)M_BOOKS * N_ROWS * 8, stream);

    dim3 blk(256, 1, 1);
    const int nz = fullM ? M_BOOKS : 1;
    const int nloop = fullM ? 1 : M_BOOKS;
    for (int p = 0; p < nloop; ++p) {
        const size_t mb = fullM ? 0 : (size_t)p;
        // encoder L1: x[N,E] @ W1[E,H1] + BN + ReLU
        gemm_fused<true><<<dim3(H1_DIM/64, N_ROWS/64, nz), blk, 0, stream>>>(
            x, eW1 + mb * (size_t)E_DIM * H1_DIM,
            eb1 + mb*H1_DIM, g1 + mb*H1_DIM, b1 + mb*H1_DIM, m1 + mb*H1_DIM, v1 + mb*H1_DIM,
            h1, E_DIM, H1_DIM,
            0, (size_t)E_DIM * H1_DIM, H1_DIM, h1N1);
        // encoder L2: h1 @ W2[H1,H2] + BN + ReLU
        gemm_fused<true><<<dim3(H2_DIM/64, N_ROWS/64, nz), blk, 0, stream>>>(
            h1, eW2 + mb * (size_t)H1_DIM * H2_DIM,
            eb2 + mb*H2_DIM, g2 + mb*H2_DIM, b2 + mb*H2_DIM, m2 + mb*H2_DIM, v2 + mb*H2_DIM,
            h2, H1_DIM, H2_DIM,
            h1N1, (size_t)H1_DIM * H2_DIM, H2_DIM, h2N1);
        // encoder L3: h2 @ W3[H2,C] + bias -> ze written straight into d_out (fp32)
        gemm_fused<false><<<dim3(C_DIM/64, N_ROWS/64, nz), blk, 0, stream>>>(
            h2, eW3 + mb * (size_t)H2_DIM * C_DIM,
            eb3 + mb*C_DIM, nullptr, nullptr, nullptr, nullptr,
            out_ze + mb * (size_t)N_ROWS * C_DIM, H2_DIM, C_DIM,
            h2N1, (size_t)H2_DIM * C_DIM, C_DIM, (size_t)N_ROWS * C_DIM);
    }

    rowsq_np<<<dim3((M_BOOKS * N_ROWS) / 256), blk, 0, stream>>>(out_ze, zesq, M_BOOKS * N_ROWS);
    rowsq_np<<<dim3((M_BOOKS * K_CODES) / 256), blk, 0, stream>>>(cb, cbsq, M_BOOKS * K_CODES);
    vq_argmin<<<dim3(K_CODES/64, N_ROWS/64, M_BOOKS), blk, 0, stream>>>(out_ze, cb, zesq, cbsq, keys);
    gather_ce_zq<<<dim3((N_ROWS * C_DIM) / 256), blk, 0, stream>>>(keys, cb, out_ce, zq);

    // decoder
    gemm_fused<true><<<dim3(H2_DIM/64, N_ROWS/64, 1), blk, 0, stream>>>(
        zq, dW1, db1, dg1, dbb1, dm1, dv1, d1, C_DIM, H2_DIM, 0, 0, 0, 0);
    gemm_fused<true><<<dim3(H1_DIM/64, N_ROWS/64, 1), blk, 0, stream>>>(
        d1, dW2, db2, dg2, dbb2, dm2, dv2, d2, H2_DIM, H1_DIM, 0, 0, 0, 0);
    gemm_fused<false><<<dim3(E_DIM/64, N_ROWS/64, 1), blk, 0, stream>>>(
        d2, dW3, db3, nullptr, nullptr, nullptr, nullptr,
        out_xhat, H1_DIM, E_DIM, 0, 0, 0, 0);
}

// Round 3
// 1009.754 us; speedup vs baseline: 1.0187x; 1.0187x over previous
//
#include <hip/hip_runtime.h>
#include <hip/hip_bf16.h>
#include <stdint.h>

#define N_ROWS 16384
#define E_DIM 512
#define C_DIM 128
#define K_CODES 2048
#define M_BOOKS 4
#define H1_DIM 128
#define H2_DIM 256
#define EPS_V 1e-5f

// ---- fused GEMM, 128x128 tile, 8x8 per thread: C = act(A@B + bias) ----
// A[N,Kd] row-major, B[Kd,Hc] row-major. blockIdx.z strides for per-book batch.
// fma chain over k ascending (BK=16 steps) == bitwise-identical to prior kernel.
template<bool BNRELU>
__global__ __launch_bounds__(256) void gemm128(
    const float* __restrict__ A, const float* __restrict__ B,
    const float* __restrict__ bias, const float* __restrict__ bn_g,
    const float* __restrict__ bn_b, const float* __restrict__ bn_m,
    const float* __restrict__ bn_v, float* __restrict__ C,
    int Kd, int Hc, size_t sA, size_t sB, size_t sP, size_t sC)
{
    __shared__ float As[16][128];   // k-major
    __shared__ float Bs[16][128];
    const int z = blockIdx.z;
    A += (size_t)z * sA;
    B += (size_t)z * sB;
    bias += (size_t)z * sP;
    if (BNRELU) {
        bn_g += (size_t)z * sP; bn_b += (size_t)z * sP;
        bn_m += (size_t)z * sP; bn_v += (size_t)z * sP;
    }

    const int t = threadIdx.x;
    const int tx = t & 15, ty = t >> 4;
    const int row0 = blockIdx.y * 128;
    const int col0 = blockIdx.x * 128;
    // A staging: row = t&127 (lanes span 64 rows -> 2-way LDS store, free)
    const int ar = t & 127;
    const int ak = (t >> 7) * 4;        // {0,4}; +8 per l -> {0,4,8,12}
    // B staging: k-major rows load straight (coalesced 512B/32 lanes)
    const int bc = (t & 31) * 4;
    const int bk0 = t >> 5;             // {0..7}; +8 per l

    float acc[8][8] = {};
    for (int k0 = 0; k0 < Kd; k0 += 16) {
        #pragma unroll
        for (int l = 0; l < 2; ++l) {
            const int lk = ak + l * 8;
            float4 av = *(const float4*)(A + (size_t)(row0 + ar) * Kd + (k0 + lk));
            As[lk+0][ar] = av.x; As[lk+1][ar] = av.y;
            As[lk+2][ar] = av.z; As[lk+3][ar] = av.w;
            const int kb = bk0 + l * 8;
            *(float4*)&Bs[kb][bc] =
                *(const float4*)(B + (size_t)(k0 + kb) * Hc + (col0 + bc));
        }
        __syncthreads();
        #pragma unroll
        for (int kk = 0; kk < 16; ++kk) {
            float a[8], b[8];
            *(float4*)&a[0] = *(const float4*)&As[kk][ty*8];
            *(float4*)&a[4] = *(const float4*)&As[kk][ty*8+4];
            *(float4*)&b[0] = *(const float4*)&Bs[kk][tx*8];
            *(float4*)&b[4] = *(const float4*)&Bs[kk][tx*8+4];
            #pragma unroll
            for (int i = 0; i < 8; ++i)
                #pragma unroll
                for (int j = 0; j < 8; ++j)
                    acc[i][j] = fmaf(a[i], b[j], acc[i][j]);
        }
        __syncthreads();
    }

    float bi[8], sc[8], mu[8], be[8];
    #pragma unroll
    for (int j = 0; j < 8; ++j) {
        const int col = col0 + tx*8 + j;
        bi[j] = bias[col];
        if (BNRELU) {
            sc[j] = bn_g[col] / sqrtf(bn_v[col] + EPS_V);
            mu[j] = bn_m[col]; be[j] = bn_b[col];
        }
    }
    #pragma unroll
    for (int i = 0; i < 8; ++i) {
        const int row = row0 + ty*8 + i;
        float v[8];
        #pragma unroll
        for (int j = 0; j < 8; ++j) {
            v[j] = acc[i][j] + bi[j];
            if (BNRELU) {
                float p = (v[j] - mu[j]) * sc[j];
                asm volatile("" : "+v"(p));   // separate rounding like numpy
                v[j] = fmaxf(p + be[j], 0.0f);
            }
        }
        float* cp = C + (size_t)z * sC + (size_t)row * Hc + col0 + tx*8;
        *(float4*)cp = *(const float4*)&v[0];
        *(float4*)(cp + 4) = *(const float4*)&v[4];
    }
}

// ---- row-wise sum of squares, emulating numpy's 8-accumulator pairwise sum ----
__global__ __launch_bounds__(256) void rowsq_np(const float* __restrict__ X,
                                                float* __restrict__ out, int rows)
{
    const int r = blockIdx.x * blockDim.x + threadIdx.x;
    if (r >= rows) return;
    const float* p = X + (size_t)r * C_DIM;
    float rr[8];
    #pragma unroll
    for (int j = 0; j < 8; ++j) {
        float v = p[j]; float s2 = v * v;
        asm volatile("" : "+v"(s2));
        rr[j] = s2;
    }
    for (int i = 8; i < C_DIM; i += 8) {
        #pragma unroll
        for (int j = 0; j < 8; ++j) {
            float v = p[i + j]; float s2 = v * v;
            asm volatile("" : "+v"(s2));    // keep mul+add separate (no fma), like np
            rr[j] = rr[j] + s2;
        }
    }
    out[r] = ((rr[0]+rr[1]) + (rr[2]+rr[3])) + ((rr[4]+rr[5]) + (rr[6]+rr[7]));
}

// ---- VQ: 128x128 cross GEMM (ze @ cb^T) fused with argmin; u64 atomicMin ----
__global__ __launch_bounds__(256) void vq_argmin(
    const float* __restrict__ ze, const float* __restrict__ cb,
    const float* __restrict__ ze_sq, const float* __restrict__ cb_sq,
    unsigned long long* __restrict__ keys)
{
    __shared__ float smem[4352];          // As/Bs (4096) then rd/ri (4352)
    float* As = smem;                     // [16][128] k-major
    float* Bs = smem + 2048;              // [16][128] k-major
    float* rd = smem;                     // [128][17]
    int*   ri = (int*)(smem + 2176);      // [128][17]

    const int m = blockIdx.z;
    const float* Zm  = ze + (size_t)m * N_ROWS * C_DIM;
    const float* Bm  = cb + (size_t)m * K_CODES * C_DIM;
    const float* zsm = ze_sq + (size_t)m * N_ROWS;
    const float* csm = cb_sq + (size_t)m * K_CODES;

    const int t = threadIdx.x;
    const int tx = t & 15, ty = t >> 4;
    const int row0 = blockIdx.y * 128;
    const int col0 = blockIdx.x * 128;
    const int ar = t & 127;
    const int ak = (t >> 7) * 4;

    float acc[8][8] = {};
    for (int k0 = 0; k0 < C_DIM; k0 += 16) {
        #pragma unroll
        for (int l = 0; l < 2; ++l) {
            const int lk = ak + l * 8;
            float4 av = *(const float4*)(Zm + (size_t)(row0 + ar) * C_DIM + (k0 + lk));
            As[(lk+0)*128+ar] = av.x; As[(lk+1)*128+ar] = av.y;
            As[(lk+2)*128+ar] = av.z; As[(lk+3)*128+ar] = av.w;
            float4 bv = *(const float4*)(Bm + (size_t)(col0 + ar) * C_DIM + (k0 + lk));
            Bs[(lk+0)*128+ar] = bv.x; Bs[(lk+1)*128+ar] = bv.y;
            Bs[(lk+2)*128+ar] = bv.z; Bs[(lk+3)*128+ar] = bv.w;
        }
        __syncthreads();
        #pragma unroll
        for (int kk = 0; kk < 16; ++kk) {
            float a[8], b[8];
            *(float4*)&a[0] = *(const float4*)&As[kk*128 + ty*8];
            *(float4*)&a[4] = *(const float4*)&As[kk*128 + ty*8+4];
            *(float4*)&b[0] = *(const float4*)&Bs[kk*128 + tx*8];
            *(float4*)&b[4] = *(const float4*)&Bs[kk*128 + tx*8+4];
            #pragma unroll
            for (int i = 0; i < 8; ++i)
                #pragma unroll
                for (int j = 0; j < 8; ++j)
                    acc[i][j] = fmaf(a[i], b[j], acc[i][j]);
        }
        __syncthreads();
    }

    // per-thread argmin over its 8 codes, per row; then stash to LDS
    #pragma unroll
    for (int i = 0; i < 8; ++i) {
        const int rloc = ty*8 + i;
        const float zs = zsm[row0 + rloc];
        float bd = 3.4e38f; int bc2 = 0;
        #pragma unroll
        for (int j = 0; j < 8; ++j) {
            const int code = col0 + tx*8 + j;
            const float d = (zs + csm[code]) - 2.0f * acc[i][j];  // reference order
            if (d < bd) { bd = d; bc2 = code; }   // strict < -> first index on ties
        }
        rd[rloc*17 + tx] = bd; ri[rloc*17 + tx] = bc2;
    }
    __syncthreads();
    if (t < 128) {
        float bd = rd[t*17]; int bc2 = ri[t*17];
        #pragma unroll
        for (int k2 = 1; k2 < 16; ++k2) {
            const float d = rd[t*17 + k2];
            if (d < bd) { bd = d; bc2 = ri[t*17 + k2]; }   // ascending code order
        }
        unsigned int ub = __float_as_uint(bd);
        ub = (ub & 0x80000000u) ? ~ub : (ub | 0x80000000u);  // monotone float->uint
        const unsigned long long key = ((unsigned long long)ub << 32) | (unsigned int)bc2;
        atomicMin(&keys[(size_t)m * N_ROWS + row0 + t], key); // ties -> smaller idx
    }
}

// ---- gather chosen codes: ce (fp32 out) + zq = sum_m ce ----
__global__ __launch_bounds__(256) void gather_ce_zq(
    const unsigned long long* __restrict__ keys, const float* __restrict__ cb,
    float* __restrict__ ce_out, float* __restrict__ zq)
{
    const int gid = blockIdx.x * 256 + threadIdx.x;
    const int n = gid >> 7, c = gid & 127;
    float s = 0.0f;
    #pragma unroll
    for (int m = 0; m < M_BOOKS; ++m) {
        const int idx = (int)(keys[(size_t)m * N_ROWS + n] & 0xFFFFFFFFull);
        const float v = cb[((size_t)m * K_CODES + idx) * C_DIM + c];
        ce_out[((size_t)m * N_ROWS + n) * (size_t)C_DIM + c] = v;
        s += v;   // sequential over m, matches np.sum(axis=0) for M=4
    }
    zq[gid] = s;
}

extern "C" void kernel_launch(void* const* d_in, const int* in_sizes, int n_in,
                              void* d_out, int out_size, void* d_ws, size_t ws_size,
                              hipStream_t stream)
{
    const float* x   = (const float*)d_in[0];
    const float* eW1 = (const float*)d_in[1];
    const float* eb1 = (const float*)d_in[2];
    const float* g1  = (const float*)d_in[3];
    const float* b1  = (const float*)d_in[4];
    const float* m1  = (const float*)d_in[5];
    const float* v1  = (const float*)d_in[6];
    const float* eW2 = (const float*)d_in[7];
    const float* eb2 = (const float*)d_in[8];
    const float* g2  = (const float*)d_in[9];
    const float* b2  = (const float*)d_in[10];
    const float* m2  = (const float*)d_in[11];
    const float* v2  = (const float*)d_in[12];
    const float* eW3 = (const float*)d_in[13];
    const float* eb3 = (const float*)d_in[14];
    const float* cb  = (const float*)d_in[15];
    const float* dW1 = (const float*)d_in[16];
    const float* db1 = (const float*)d_in[17];
    const float* dg1 = (const float*)d_in[18];
    const float* dbb1= (const float*)d_in[19];
    const float* dm1 = (const float*)d_in[20];
    const float* dv1 = (const float*)d_in[21];
    const float* dW2 = (const float*)d_in[22];
    const float* db2 = (const float*)d_in[23];
    const float* dg2 = (const float*)d_in[24];
    const float* dbb2= (const float*)d_in[25];
    const float* dm2 = (const float*)d_in[26];
    const float* dv2 = (const float*)d_in[27];
    const float* dW3 = (const float*)d_in[28];
    const float* db3 = (const float*)d_in[29];

    // Outputs are FLOAT32: x_hat[N,E], ze[M,N,C], ce[M,N,C]
    float* out_xhat = (float*)d_out;
    float* out_ze   = out_xhat + (size_t)N_ROWS * E_DIM;
    float* out_ce   = out_ze + (size_t)M_BOOKS * N_ROWS * C_DIM;

    float* ws = (float*)d_ws;
    const size_t h1N1 = (size_t)N_ROWS * H1_DIM;           // 2097152
    const size_t h2N1 = (size_t)N_ROWS * H2_DIM;           // 4194304
    const size_t smallN = (size_t)M_BOOKS*N_ROWS + (size_t)M_BOOKS*K_CODES
                        + 2 + 2*(size_t)M_BOOKS*N_ROWS;
    const size_t fullFloats = (size_t)M_BOOKS*(h1N1 + h2N1) + smallN;
    const bool fullM = ws_size >= fullFloats * sizeof(float) + 256;

    size_t off = 0;
    float* h1 = ws; off += (fullM ? M_BOOKS : 1) * h1N1;
    float* h2 = ws + off; off += (fullM ? M_BOOKS : 1) * h2N1;
    float* zesq = ws + off; off += (size_t)M_BOOKS * N_ROWS;
    float* cbsq = ws + off; off += (size_t)M_BOOKS * K_CODES;
    off = (off + 1) & ~(size_t)1;
    unsigned long long* keys = (unsigned long long*)(ws + off);
    float* zq = h1;   // reuse after encoders finish
    float* d1 = h2;
    float* d2 = h1;   // zq dead once decoder L1 done

    hipMemsetAsync((void*)keys, 0xFF, (size_t)M_BOOKS * N_ROWS * 8, stream);

    dim3 blk(256, 1, 1);
    const int nz = fullM ? M_BOOKS : 1;
    const int nloop = fullM ? 1 : M_BOOKS;
    for (int p = 0; p < nloop; ++p) {
        const size_t mb = fullM ? 0 : (size_t)p;
        // encoder L1: x[N,E] @ W1[E,H1] + BN + ReLU
        gemm128<true><<<dim3(H1_DIM/128, N_ROWS/128, nz), blk, 0, stream>>>(
            x, eW1 + mb * (size_t)E_DIM * H1_DIM,
            eb1 + mb*H1_DIM, g1 + mb*H1_DIM, b1 + mb*H1_DIM, m1 + mb*H1_DIM, v1 + mb*H1_DIM,
            h1, E_DIM, H1_DIM,
            0, (size_t)E_DIM * H1_DIM, H1_DIM, h1N1);
        // encoder L2: h1 @ W2[H1,H2] + BN + ReLU
        gemm128<true><<<dim3(H2_DIM/128, N_ROWS/128, nz), blk, 0, stream>>>(
            h1, eW2 + mb * (size_t)H1_DIM * H2_DIM,
            eb2 + mb*H2_DIM, g2 + mb*H2_DIM, b2 + mb*H2_DIM, m2 + mb*H2_DIM, v2 + mb*H2_DIM,
            h2, H1_DIM, H2_DIM,
            h1N1, (size_t)H1_DIM * H2_DIM, H2_DIM, h2N1);
        // encoder L3: h2 @ W3[H2,C] + bias -> ze straight into d_out (fp32)
        gemm128<false><<<dim3(C_DIM/128, N_ROWS/128, nz), blk, 0, stream>>>(
            h2, eW3 + mb * (size_t)H2_DIM * C_DIM,
            eb3 + mb*C_DIM, nullptr, nullptr, nullptr, nullptr,
            out_ze + mb * (size_t)N_ROWS * C_DIM, H2_DIM, C_DIM,
            h2N1, (size_t)H2_DIM * C_DIM, C_DIM, (size_t)N_ROWS * C_DIM);
    }

    rowsq_np<<<dim3((M_BOOKS * N_ROWS) / 256), blk, 0, stream>>>(out_ze, zesq, M_BOOKS * N_ROWS);
    rowsq_np<<<dim3((M_BOOKS * K_CODES) / 256), blk, 0, stream>>>(cb, cbsq, M_BOOKS * K_CODES);
    vq_argmin<<<dim3(K_CODES/128, N_ROWS/128, M_BOOKS), blk, 0, stream>>>(
        out_ze, cb, zesq, cbsq, keys);
    gather_ce_zq<<<dim3((N_ROWS * C_DIM) / 256), blk, 0, stream>>>(keys, cb, out_ce, zq);

    // decoder
    gemm128<true><<<dim3(H2_DIM/128, N_ROWS/128, 1), blk, 0, stream>>>(
        zq, dW1, db1, dg1, dbb1, dm1, dv1, d1, C_DIM, H2_DIM, 0, 0, 0, 0);
    gemm128<true><<<dim3(H1_DIM/128, N_ROWS/128, 1), blk, 0, stream>>>(
        d1, dW2, db2, dg2, dbb2, dm2, dv2, d2, H2_DIM, H1_DIM, 0, 0, 0, 0);
    gemm128<false><<<dim3(E_DIM/128, N_ROWS/128, 1), blk, 0, stream>>>(
        d2, dW3, db3, nullptr, nullptr, nullptr, nullptr,
        out_xhat, H1_DIM, E_DIM, 0, 0, 0, 0);
}

// Round 4
// 779.733 us; speedup vs baseline: 1.3192x; 1.2950x over previous
//
#include <hip/hip_runtime.h>
#include <hip/hip_bf16.h>
#include <stdint.h>

#define N_ROWS 16384
#define E_DIM 512
#define C_DIM 128
#define K_CODES 2048
#define M_BOOKS 4
#define H1_DIM 128
#define H2_DIM 256
#define EPS_V 1e-5f

// ---- fused GEMM, 128x128 tile, 8x8 per thread (split 4+4 row/col groups) ----
// A[N,Kd] row-major, B[Kd,Hc] row-major. blockIdx.z strides for per-book batch.
// Thread (tx,ty) owns rows {ty*4+i, 64+ty*4+i}, cols {tx*4+j, 64+tx*4+j}:
// fragment ds_reads are 16B at 16B lane stride (2-way, free) or broadcast.
// fma chain over k ascending == bitwise-identical to round-2 kernel.
template<bool BNRELU>
__global__ __launch_bounds__(256) void gemm128(
    const float* __restrict__ A, const float* __restrict__ B,
    const float* __restrict__ bias, const float* __restrict__ bn_g,
    const float* __restrict__ bn_b, const float* __restrict__ bn_m,
    const float* __restrict__ bn_v, float* __restrict__ C,
    int Kd, int Hc, size_t sA, size_t sB, size_t sP, size_t sC)
{
    __shared__ float As[16][128];   // k-major
    __shared__ float Bs[16][128];
    const int z = blockIdx.z;
    A += (size_t)z * sA;
    B += (size_t)z * sB;
    bias += (size_t)z * sP;
    if (BNRELU) {
        bn_g += (size_t)z * sP; bn_b += (size_t)z * sP;
        bn_m += (size_t)z * sP; bn_v += (size_t)z * sP;
    }

    const int t = threadIdx.x;
    const int tx = t & 15, ty = t >> 4;
    const int row0 = blockIdx.y * 128;
    const int col0 = blockIdx.x * 128;
    const int ar = t & 127;             // A staging: 2-way store, free
    const int ak = (t >> 7) * 4;        // {0,4}; +8 per l
    const int bc = (t & 31) * 4;        // B staging: 2-way store, free
    const int bk0 = t >> 5;

    float acc[8][8] = {};
    for (int k0 = 0; k0 < Kd; k0 += 16) {
        #pragma unroll
        for (int l = 0; l < 2; ++l) {
            const int lk = ak + l * 8;
            float4 av = *(const float4*)(A + (size_t)(row0 + ar) * Kd + (k0 + lk));
            As[lk+0][ar] = av.x; As[lk+1][ar] = av.y;
            As[lk+2][ar] = av.z; As[lk+3][ar] = av.w;
            const int kb = bk0 + l * 8;
            *(float4*)&Bs[kb][bc] =
                *(const float4*)(B + (size_t)(k0 + kb) * Hc + (col0 + bc));
        }
        __syncthreads();
        #pragma unroll
        for (int kk = 0; kk < 16; ++kk) {
            float a[8], b[8];
            *(float4*)&a[0] = *(const float4*)&As[kk][ty*4];        // broadcast
            *(float4*)&a[4] = *(const float4*)&As[kk][64 + ty*4];   // broadcast
            *(float4*)&b[0] = *(const float4*)&Bs[kk][tx*4];        // 2-way
            *(float4*)&b[4] = *(const float4*)&Bs[kk][64 + tx*4];   // 2-way
            #pragma unroll
            for (int i = 0; i < 8; ++i)
                #pragma unroll
                for (int j = 0; j < 8; ++j)
                    acc[i][j] = fmaf(a[i], b[j], acc[i][j]);
        }
        __syncthreads();
    }

    float bi[8], sc[8], mu[8], be[8];
    #pragma unroll
    for (int j = 0; j < 8; ++j) {
        const int col = col0 + ((j < 4) ? (tx*4 + j) : (64 + tx*4 + j - 4));
        bi[j] = bias[col];
        if (BNRELU) {
            sc[j] = bn_g[col] / sqrtf(bn_v[col] + EPS_V);
            mu[j] = bn_m[col]; be[j] = bn_b[col];
        }
    }
    #pragma unroll
    for (int i = 0; i < 8; ++i) {
        const int row = row0 + ((i < 4) ? (ty*4 + i) : (64 + ty*4 + i - 4));
        float v[8];
        #pragma unroll
        for (int j = 0; j < 8; ++j) {
            v[j] = acc[i][j] + bi[j];
            if (BNRELU) {
                float p = (v[j] - mu[j]) * sc[j];
                asm volatile("" : "+v"(p));   // separate rounding like numpy
                v[j] = fmaxf(p + be[j], 0.0f);
            }
        }
        float* cp = C + (size_t)z * sC + (size_t)row * Hc + col0;
        *(float4*)(cp + tx*4)      = *(const float4*)&v[0];
        *(float4*)(cp + 64 + tx*4) = *(const float4*)&v[4];
    }
}

// ---- row-wise sum of squares, emulating numpy's 8-accumulator pairwise sum ----
__global__ __launch_bounds__(256) void rowsq_np(const float* __restrict__ X,
                                                float* __restrict__ out, int rows)
{
    const int r = blockIdx.x * blockDim.x + threadIdx.x;
    if (r >= rows) return;
    const float* p = X + (size_t)r * C_DIM;
    float rr[8];
    #pragma unroll
    for (int j = 0; j < 8; ++j) {
        float v = p[j]; float s2 = v * v;
        asm volatile("" : "+v"(s2));
        rr[j] = s2;
    }
    for (int i = 8; i < C_DIM; i += 8) {
        #pragma unroll
        for (int j = 0; j < 8; ++j) {
            float v = p[i + j]; float s2 = v * v;
            asm volatile("" : "+v"(s2));    // keep mul+add separate (no fma), like np
            rr[j] = rr[j] + s2;
        }
    }
    out[r] = ((rr[0]+rr[1]) + (rr[2]+rr[3])) + ((rr[4]+rr[5]) + (rr[6]+rr[7]));
}

// ---- VQ: 128x128 cross GEMM (ze @ cb^T) fused with argmin ----
// Per-thread best -> u64 (distbits<<32|code) key; LDS u64-min across 16 threads
// (lexicographic == first-index argmin); global merge via atomicMin.
__global__ __launch_bounds__(256) void vq_argmin(
    const float* __restrict__ ze, const float* __restrict__ cb,
    const float* __restrict__ ze_sq, const float* __restrict__ cb_sq,
    unsigned long long* __restrict__ keys)
{
    __shared__ __align__(16) char smem_raw[17408];
    float* As = (float*)smem_raw;                       // [16][128]
    float* Bs = As + 2048;                              // [16][128]
    unsigned long long* kb = (unsigned long long*)smem_raw;  // [128][17] after reuse

    const int m = blockIdx.z;
    const float* Zm  = ze + (size_t)m * N_ROWS * C_DIM;
    const float* Bm  = cb + (size_t)m * K_CODES * C_DIM;
    const float* zsm = ze_sq + (size_t)m * N_ROWS;
    const float* csm = cb_sq + (size_t)m * K_CODES;

    const int t = threadIdx.x;
    const int tx = t & 15, ty = t >> 4;
    const int row0 = blockIdx.y * 128;
    const int col0 = blockIdx.x * 128;
    const int ar = t & 127;
    const int ak = (t >> 7) * 4;

    float acc[8][8] = {};
    for (int k0 = 0; k0 < C_DIM; k0 += 16) {
        #pragma unroll
        for (int l = 0; l < 2; ++l) {
            const int lk = ak + l * 8;
            float4 av = *(const float4*)(Zm + (size_t)(row0 + ar) * C_DIM + (k0 + lk));
            As[(lk+0)*128+ar] = av.x; As[(lk+1)*128+ar] = av.y;
            As[(lk+2)*128+ar] = av.z; As[(lk+3)*128+ar] = av.w;
            float4 bv = *(const float4*)(Bm + (size_t)(col0 + ar) * C_DIM + (k0 + lk));
            Bs[(lk+0)*128+ar] = bv.x; Bs[(lk+1)*128+ar] = bv.y;
            Bs[(lk+2)*128+ar] = bv.z; Bs[(lk+3)*128+ar] = bv.w;
        }
        __syncthreads();
        #pragma unroll
        for (int kk = 0; kk < 16; ++kk) {
            float a[8], b[8];
            *(float4*)&a[0] = *(const float4*)&As[kk*128 + ty*4];
            *(float4*)&a[4] = *(const float4*)&As[kk*128 + 64 + ty*4];
            *(float4*)&b[0] = *(const float4*)&Bs[kk*128 + tx*4];
            *(float4*)&b[4] = *(const float4*)&Bs[kk*128 + 64 + tx*4];
            #pragma unroll
            for (int i = 0; i < 8; ++i)
                #pragma unroll
                for (int j = 0; j < 8; ++j)
                    acc[i][j] = fmaf(a[i], b[j], acc[i][j]);
        }
        __syncthreads();
    }

    // per-thread best over its 8 codes for each of its 8 rows -> u64 keys in LDS
    unsigned long long mykey[8];
    #pragma unroll
    for (int i = 0; i < 8; ++i) {
        const int rloc = (i < 4) ? (ty*4 + i) : (64 + ty*4 + i - 4);
        const float zs = zsm[row0 + rloc];
        unsigned long long bk = 0xFFFFFFFFFFFFFFFFull;
        #pragma unroll
        for (int j = 0; j < 8; ++j) {
            const int code = col0 + ((j < 4) ? (tx*4 + j) : (64 + tx*4 + j - 4));
            const float d = (zs + csm[code]) - 2.0f * acc[i][j];  // reference order
            unsigned int ub = __float_as_uint(d);
            ub = (ub & 0x80000000u) ? ~ub : (ub | 0x80000000u);   // monotone map
            const unsigned long long key =
                ((unsigned long long)ub << 32) | (unsigned int)code;
            bk = (key < bk) ? key : bk;     // lexicographic (dist, code) min
        }
        mykey[i] = bk;
    }
    __syncthreads();   // done with As/Bs; reuse LDS for keys
    #pragma unroll
    for (int i = 0; i < 8; ++i) {
        const int rloc = (i < 4) ? (ty*4 + i) : (64 + ty*4 + i - 4);
        kb[rloc*17 + tx] = mykey[i];
    }
    __syncthreads();
    if (t < 128) {
        unsigned long long bk = kb[t*17];
        #pragma unroll
        for (int k2 = 1; k2 < 16; ++k2) {
            const unsigned long long k = kb[t*17 + k2];
            bk = (k < bk) ? k : bk;
        }
        atomicMin(&keys[(size_t)m * N_ROWS + row0 + t], bk);
    }
}

// ---- gather chosen codes: ce (fp32 out) + zq = sum_m ce ----
__global__ __launch_bounds__(256) void gather_ce_zq(
    const unsigned long long* __restrict__ keys, const float* __restrict__ cb,
    float* __restrict__ ce_out, float* __restrict__ zq)
{
    const int gid = blockIdx.x * 256 + threadIdx.x;
    const int n = gid >> 7, c = gid & 127;
    float s = 0.0f;
    #pragma unroll
    for (int m = 0; m < M_BOOKS; ++m) {
        const int idx = (int)(keys[(size_t)m * N_ROWS + n] & 0xFFFFFFFFull);
        const float v = cb[((size_t)m * K_CODES + idx) * C_DIM + c];
        ce_out[((size_t)m * N_ROWS + n) * (size_t)C_DIM + c] = v;
        s += v;   // sequential over m, matches np.sum(axis=0) for M=4
    }
    zq[gid] = s;
}

extern "C" void kernel_launch(void* const* d_in, const int* in_sizes, int n_in,
                              void* d_out, int out_size, void* d_ws, size_t ws_size,
                              hipStream_t stream)
{
    const float* x   = (const float*)d_in[0];
    const float* eW1 = (const float*)d_in[1];
    const float* eb1 = (const float*)d_in[2];
    const float* g1  = (const float*)d_in[3];
    const float* b1  = (const float*)d_in[4];
    const float* m1  = (const float*)d_in[5];
    const float* v1  = (const float*)d_in[6];
    const float* eW2 = (const float*)d_in[7];
    const float* eb2 = (const float*)d_in[8];
    const float* g2  = (const float*)d_in[9];
    const float* b2  = (const float*)d_in[10];
    const float* m2  = (const float*)d_in[11];
    const float* v2  = (const float*)d_in[12];
    const float* eW3 = (const float*)d_in[13];
    const float* eb3 = (const float*)d_in[14];
    const float* cb  = (const float*)d_in[15];
    const float* dW1 = (const float*)d_in[16];
    const float* db1 = (const float*)d_in[17];
    const float* dg1 = (const float*)d_in[18];
    const float* dbb1= (const float*)d_in[19];
    const float* dm1 = (const float*)d_in[20];
    const float* dv1 = (const float*)d_in[21];
    const float* dW2 = (const float*)d_in[22];
    const float* db2 = (const float*)d_in[23];
    const float* dg2 = (const float*)d_in[24];
    const float* dbb2= (const float*)d_in[25];
    const float* dm2 = (const float*)d_in[26];
    const float* dv2 = (const float*)d_in[27];
    const float* dW3 = (const float*)d_in[28];
    const float* db3 = (const float*)d_in[29];

    // Outputs are FLOAT32: x_hat[N,E], ze[M,N,C], ce[M,N,C]
    float* out_xhat = (float*)d_out;
    float* out_ze   = out_xhat + (size_t)N_ROWS * E_DIM;
    float* out_ce   = out_ze + (size_t)M_BOOKS * N_ROWS * C_DIM;

    float* ws = (float*)d_ws;
    const size_t h1N1 = (size_t)N_ROWS * H1_DIM;           // 2097152
    const size_t h2N1 = (size_t)N_ROWS * H2_DIM;           // 4194304
    const size_t smallN = (size_t)M_BOOKS*N_ROWS + (size_t)M_BOOKS*K_CODES
                        + 2 + 2*(size_t)M_BOOKS*N_ROWS;
    const size_t fullFloats = (size_t)M_BOOKS*(h1N1 + h2N1) + smallN;
    const bool fullM = ws_size >= fullFloats * sizeof(float) + 256;

    size_t off = 0;
    float* h1 = ws; off += (fullM ? M_BOOKS : 1) * h1N1;
    float* h2 = ws + off; off += (fullM ? M_BOOKS : 1) * h2N1;
    float* zesq = ws + off; off += (size_t)M_BOOKS * N_ROWS;
    float* cbsq = ws + off; off += (size_t)M_BOOKS * K_CODES;
    off = (off + 1) & ~(size_t)1;
    unsigned long long* keys = (unsigned long long*)(ws + off);
    float* zq = h1;   // reuse after encoders finish
    float* d1 = h2;
    float* d2 = h1;   // zq dead once decoder L1 done

    hipMemsetAsync((void*)keys, 0xFF, (size_t)M_BOOKS * N_ROWS * 8, stream);

    dim3 blk(256, 1, 1);
    const int nz = fullM ? M_BOOKS : 1;
    const int nloop = fullM ? 1 : M_BOOKS;
    for (int p = 0; p < nloop; ++p) {
        const size_t mb = fullM ? 0 : (size_t)p;
        // encoder L1: x[N,E] @ W1[E,H1] + BN + ReLU
        gemm128<true><<<dim3(H1_DIM/128, N_ROWS/128, nz), blk, 0, stream>>>(
            x, eW1 + mb * (size_t)E_DIM * H1_DIM,
            eb1 + mb*H1_DIM, g1 + mb*H1_DIM, b1 + mb*H1_DIM, m1 + mb*H1_DIM, v1 + mb*H1_DIM,
            h1, E_DIM, H1_DIM,
            0, (size_t)E_DIM * H1_DIM, H1_DIM, h1N1);
        // encoder L2: h1 @ W2[H1,H2] + BN + ReLU
        gemm128<true><<<dim3(H2_DIM/128, N_ROWS/128, nz), blk, 0, stream>>>(
            h1, eW2 + mb * (size_t)H1_DIM * H2_DIM,
            eb2 + mb*H2_DIM, g2 + mb*H2_DIM, b2 + mb*H2_DIM, m2 + mb*H2_DIM, v2 + mb*H2_DIM,
            h2, H1_DIM, H2_DIM,
            h1N1, (size_t)H1_DIM * H2_DIM, H2_DIM, h2N1);
        // encoder L3: h2 @ W3[H2,C] + bias -> ze straight into d_out (fp32)
        gemm128<false><<<dim3(C_DIM/128, N_ROWS/128, nz), blk, 0, stream>>>(
            h2, eW3 + mb * (size_t)H2_DIM * C_DIM,
            eb3 + mb*C_DIM, nullptr, nullptr, nullptr, nullptr,
            out_ze + mb * (size_t)N_ROWS * C_DIM, H2_DIM, C_DIM,
            h2N1, (size_t)H2_DIM * C_DIM, C_DIM, (size_t)N_ROWS * C_DIM);
    }

    rowsq_np<<<dim3((M_BOOKS * N_ROWS) / 256), blk, 0, stream>>>(out_ze, zesq, M_BOOKS * N_ROWS);
    rowsq_np<<<dim3((M_BOOKS * K_CODES) / 256), blk, 0, stream>>>(cb, cbsq, M_BOOKS * K_CODES);
    vq_argmin<<<dim3(K_CODES/128, N_ROWS/128, M_BOOKS), blk, 0, stream>>>(
        out_ze, cb, zesq, cbsq, keys);
    gather_ce_zq<<<dim3((N_ROWS * C_DIM) / 256), blk, 0, stream>>>(keys, cb, out_ce, zq);

    // decoder
    gemm128<true><<<dim3(H2_DIM/128, N_ROWS/128, 1), blk, 0, stream>>>(
        zq, dW1, db1, dg1, dbb1, dm1, dv1, d1, C_DIM, H2_DIM, 0, 0, 0, 0);
    gemm128<true><<<dim3(H1_DIM/128, N_ROWS/128, 1), blk, 0, stream>>>(
        d1, dW2, db2, dg2, dbb2, dm2, dv2, d2, H2_DIM, H1_DIM, 0, 0, 0, 0);
    gemm128<false><<<dim3(E_DIM/128, N_ROWS/128, 1), blk, 0, stream>>>(
        d2, dW3, db3, nullptr, nullptr, nullptr, nullptr,
        out_xhat, H1_DIM, E_DIM, 0, 0, 0, 0);
}

// Round 5
// 776.627 us; speedup vs baseline: 1.3245x; 1.0040x over previous
//
#include <hip/hip_runtime.h>
#include <hip/hip_bf16.h>
#include <stdint.h>

#define N_ROWS 16384
#define E_DIM 512
#define C_DIM 128
#define K_CODES 2048
#define M_BOOKS 4
#define H1_DIM 128
#define H2_DIM 256
#define EPS_V 1e-5f

// ---- fused GEMM, 128x128 tile, 8x8 per thread (split 4+4 row/col groups) ----
// __launch_bounds__(256,4): 128-VGPR budget so acc[8][8] stays in arch VGPRs
// (bare bounds targeted 8 waves/EU -> 64-VGPR budget -> acc in AGPRs -> 2
//  v_accvgpr moves per FMA; VGPR_Count=60 + 54% useful vs 84% busy was the tell).
// fma chain over k ascending (any BK) == bitwise-identical to prior rounds.
template<int BK, bool BNRELU>
__global__ __launch_bounds__(256, 4) void gemm128(
    const float* __restrict__ A, const float* __restrict__ B,
    const float* __restrict__ bias, const float* __restrict__ bn_g,
    const float* __restrict__ bn_b, const float* __restrict__ bn_m,
    const float* __restrict__ bn_v, float* __restrict__ C,
    int Kd, int Hc, size_t sA, size_t sB, size_t sP, size_t sC)
{
    __shared__ float As[BK][128];   // k-major
    __shared__ float Bs[BK][128];
    const int z = blockIdx.z;
    A += (size_t)z * sA;
    B += (size_t)z * sB;
    bias += (size_t)z * sP;
    if (BNRELU) {
        bn_g += (size_t)z * sP; bn_b += (size_t)z * sP;
        bn_m += (size_t)z * sP; bn_v += (size_t)z * sP;
    }

    const int t = threadIdx.x;
    const int tx = t & 15, ty = t >> 4;
    const int row0 = blockIdx.y * 128;
    const int col0 = blockIdx.x * 128;
    const int ar = t & 127;             // A staging: 2-way store, free
    const int ak = (t >> 7) * 4;        // {0,4}; +8 per l
    const int bc = (t & 31) * 4;        // B staging: linear, free
    const int bk0 = t >> 5;

    float acc[8][8] = {};
    for (int k0 = 0; k0 < Kd; k0 += BK) {
        #pragma unroll
        for (int l = 0; l < BK / 8; ++l) {
            const int lk = ak + l * 8;
            float4 av = *(const float4*)(A + (size_t)(row0 + ar) * Kd + (k0 + lk));
            As[lk+0][ar] = av.x; As[lk+1][ar] = av.y;
            As[lk+2][ar] = av.z; As[lk+3][ar] = av.w;
            const int kb = bk0 + l * 8;
            *(float4*)&Bs[kb][bc] =
                *(const float4*)(B + (size_t)(k0 + kb) * Hc + (col0 + bc));
        }
        __syncthreads();
        #pragma unroll
        for (int kk = 0; kk < BK; ++kk) {
            float a[8], b[8];
            *(float4*)&a[0] = *(const float4*)&As[kk][ty*4];        // broadcast
            *(float4*)&a[4] = *(const float4*)&As[kk][64 + ty*4];   // broadcast
            *(float4*)&b[0] = *(const float4*)&Bs[kk][tx*4];        // 2-way
            *(float4*)&b[4] = *(const float4*)&Bs[kk][64 + tx*4];   // 2-way
            #pragma unroll
            for (int i = 0; i < 8; ++i)
                #pragma unroll
                for (int j = 0; j < 8; ++j)
                    acc[i][j] = fmaf(a[i], b[j], acc[i][j]);
        }
        __syncthreads();
    }

    float bi[8], sc[8], mu[8], be[8];
    #pragma unroll
    for (int j = 0; j < 8; ++j) {
        const int col = col0 + ((j < 4) ? (tx*4 + j) : (64 + tx*4 + j - 4));
        bi[j] = bias[col];
        if (BNRELU) {
            sc[j] = bn_g[col] / sqrtf(bn_v[col] + EPS_V);
            mu[j] = bn_m[col]; be[j] = bn_b[col];
        }
    }
    #pragma unroll
    for (int i = 0; i < 8; ++i) {
        const int row = row0 + ((i < 4) ? (ty*4 + i) : (64 + ty*4 + i - 4));
        float v[8];
        #pragma unroll
        for (int j = 0; j < 8; ++j) {
            v[j] = acc[i][j] + bi[j];
            if (BNRELU) {
                float p = (v[j] - mu[j]) * sc[j];
                asm volatile("" : "+v"(p));   // separate rounding like numpy
                v[j] = fmaxf(p + be[j], 0.0f);
            }
        }
        float* cp = C + (size_t)z * sC + (size_t)row * Hc + col0;
        *(float4*)(cp + tx*4)      = *(const float4*)&v[0];
        *(float4*)(cp + 64 + tx*4) = *(const float4*)&v[4];
    }
}

// ---- row-wise sum of squares, emulating numpy's 8-accumulator pairwise sum ----
__global__ __launch_bounds__(256) void rowsq_np(const float* __restrict__ X,
                                                float* __restrict__ out, int rows)
{
    const int r = blockIdx.x * blockDim.x + threadIdx.x;
    if (r >= rows) return;
    const float* p = X + (size_t)r * C_DIM;
    float rr[8];
    #pragma unroll
    for (int j = 0; j < 8; ++j) {
        float v = p[j]; float s2 = v * v;
        asm volatile("" : "+v"(s2));
        rr[j] = s2;
    }
    for (int i = 8; i < C_DIM; i += 8) {
        #pragma unroll
        for (int j = 0; j < 8; ++j) {
            float v = p[i + j]; float s2 = v * v;
            asm volatile("" : "+v"(s2));    // keep mul+add separate (no fma), like np
            rr[j] = rr[j] + s2;
        }
    }
    out[r] = ((rr[0]+rr[1]) + (rr[2]+rr[3])) + ((rr[4]+rr[5]) + (rr[6]+rr[7]));
}

// ---- VQ: 128x128 cross GEMM (ze @ cb^T) fused with argmin ----
// Per-thread best -> u64 (distbits<<32|code) key; LDS u64-min across 16 threads
// (lexicographic == first-index argmin); global merge via atomicMin.
__global__ __launch_bounds__(256, 4) void vq_argmin(
    const float* __restrict__ ze, const float* __restrict__ cb,
    const float* __restrict__ ze_sq, const float* __restrict__ cb_sq,
    unsigned long long* __restrict__ keys)
{
    __shared__ __align__(16) char smem_raw[32768];
    float* As = (float*)smem_raw;                       // [32][128]
    float* Bs = As + 32*128;                            // [32][128]
    unsigned long long* kb = (unsigned long long*)smem_raw;  // [128][17] overlay

    const int m = blockIdx.z;
    const float* Zm  = ze + (size_t)m * N_ROWS * C_DIM;
    const float* Bm  = cb + (size_t)m * K_CODES * C_DIM;
    const float* zsm = ze_sq + (size_t)m * N_ROWS;
    const float* csm = cb_sq + (size_t)m * K_CODES;

    const int t = threadIdx.x;
    const int tx = t & 15, ty = t >> 4;
    const int row0 = blockIdx.y * 128;
    const int col0 = blockIdx.x * 128;
    const int ar = t & 127;
    const int ak = (t >> 7) * 4;

    float acc[8][8] = {};
    for (int k0 = 0; k0 < C_DIM; k0 += 32) {
        #pragma unroll
        for (int l = 0; l < 4; ++l) {
            const int lk = ak + l * 8;
            float4 av = *(const float4*)(Zm + (size_t)(row0 + ar) * C_DIM + (k0 + lk));
            As[(lk+0)*128+ar] = av.x; As[(lk+1)*128+ar] = av.y;
            As[(lk+2)*128+ar] = av.z; As[(lk+3)*128+ar] = av.w;
            float4 bv = *(const float4*)(Bm + (size_t)(col0 + ar) * C_DIM + (k0 + lk));
            Bs[(lk+0)*128+ar] = bv.x; Bs[(lk+1)*128+ar] = bv.y;
            Bs[(lk+2)*128+ar] = bv.z; Bs[(lk+3)*128+ar] = bv.w;
        }
        __syncthreads();
        #pragma unroll
        for (int kk = 0; kk < 32; ++kk) {
            float a[8], b[8];
            *(float4*)&a[0] = *(const float4*)&As[kk*128 + ty*4];
            *(float4*)&a[4] = *(const float4*)&As[kk*128 + 64 + ty*4];
            *(float4*)&b[0] = *(const float4*)&Bs[kk*128 + tx*4];
            *(float4*)&b[4] = *(const float4*)&Bs[kk*128 + 64 + tx*4];
            #pragma unroll
            for (int i = 0; i < 8; ++i)
                #pragma unroll
                for (int j = 0; j < 8; ++j)
                    acc[i][j] = fmaf(a[i], b[j], acc[i][j]);
        }
        __syncthreads();
    }

    // per-thread best over its 8 codes for each of its 8 rows -> u64 keys in LDS
    unsigned long long mykey[8];
    #pragma unroll
    for (int i = 0; i < 8; ++i) {
        const int rloc = (i < 4) ? (ty*4 + i) : (64 + ty*4 + i - 4);
        const float zs = zsm[row0 + rloc];
        unsigned long long bk = 0xFFFFFFFFFFFFFFFFull;
        #pragma unroll
        for (int j = 0; j < 8; ++j) {
            const int code = col0 + ((j < 4) ? (tx*4 + j) : (64 + tx*4 + j - 4));
            const float d = (zs + csm[code]) - 2.0f * acc[i][j];  // reference order
            unsigned int ub = __float_as_uint(d);
            ub = (ub & 0x80000000u) ? ~ub : (ub | 0x80000000u);   // monotone map
            const unsigned long long key =
                ((unsigned long long)ub << 32) | (unsigned int)code;
            bk = (key < bk) ? key : bk;     // lexicographic (dist, code) min
        }
        mykey[i] = bk;
    }
    __syncthreads();   // done with As/Bs; reuse LDS for keys
    #pragma unroll
    for (int i = 0; i < 8; ++i) {
        const int rloc = (i < 4) ? (ty*4 + i) : (64 + ty*4 + i - 4);
        kb[rloc*17 + tx] = mykey[i];
    }
    __syncthreads();
    if (t < 128) {
        unsigned long long bk = kb[t*17];
        #pragma unroll
        for (int k2 = 1; k2 < 16; ++k2) {
            const unsigned long long k = kb[t*17 + k2];
            bk = (k < bk) ? k : bk;
        }
        atomicMin(&keys[(size_t)m * N_ROWS + row0 + t], bk);
    }
}

// ---- gather chosen codes: ce (fp32 out) + zq = sum_m ce ----
__global__ __launch_bounds__(256) void gather_ce_zq(
    const unsigned long long* __restrict__ keys, const float* __restrict__ cb,
    float* __restrict__ ce_out, float* __restrict__ zq)
{
    const int gid = blockIdx.x * 256 + threadIdx.x;
    const int n = gid >> 7, c = gid & 127;
    float s = 0.0f;
    #pragma unroll
    for (int m = 0; m < M_BOOKS; ++m) {
        const int idx = (int)(keys[(size_t)m * N_ROWS + n] & 0xFFFFFFFFull);
        const float v = cb[((size_t)m * K_CODES + idx) * C_DIM + c];
        ce_out[((size_t)m * N_ROWS + n) * (size_t)C_DIM + c] = v;
        s += v;   // sequential over m, matches np.sum(axis=0) for M=4
    }
    zq[gid] = s;
}

extern "C" void kernel_launch(void* const* d_in, const int* in_sizes, int n_in,
                              void* d_out, int out_size, void* d_ws, size_t ws_size,
                              hipStream_t stream)
{
    const float* x   = (const float*)d_in[0];
    const float* eW1 = (const float*)d_in[1];
    const float* eb1 = (const float*)d_in[2];
    const float* g1  = (const float*)d_in[3];
    const float* b1  = (const float*)d_in[4];
    const float* m1  = (const float*)d_in[5];
    const float* v1  = (const float*)d_in[6];
    const float* eW2 = (const float*)d_in[7];
    const float* eb2 = (const float*)d_in[8];
    const float* g2  = (const float*)d_in[9];
    const float* b2  = (const float*)d_in[10];
    const float* m2  = (const float*)d_in[11];
    const float* v2  = (const float*)d_in[12];
    const float* eW3 = (const float*)d_in[13];
    const float* eb3 = (const float*)d_in[14];
    const float* cb  = (const float*)d_in[15];
    const float* dW1 = (const float*)d_in[16];
    const float* db1 = (const float*)d_in[17];
    const float* dg1 = (const float*)d_in[18];
    const float* dbb1= (const float*)d_in[19];
    const float* dm1 = (const float*)d_in[20];
    const float* dv1 = (const float*)d_in[21];
    const float* dW2 = (const float*)d_in[22];
    const float* db2 = (const float*)d_in[23];
    const float* dg2 = (const float*)d_in[24];
    const float* dbb2= (const float*)d_in[25];
    const float* dm2 = (const float*)d_in[26];
    const float* dv2 = (const float*)d_in[27];
    const float* dW3 = (const float*)d_in[28];
    const float* db3 = (const float*)d_in[29];

    // Outputs are FLOAT32: x_hat[N,E], ze[M,N,C], ce[M,N,C]
    float* out_xhat = (float*)d_out;
    float* out_ze   = out_xhat + (size_t)N_ROWS * E_DIM;
    float* out_ce   = out_ze + (size_t)M_BOOKS * N_ROWS * C_DIM;

    float* ws = (float*)d_ws;
    const size_t h1N1 = (size_t)N_ROWS * H1_DIM;           // 2097152
    const size_t h2N1 = (size_t)N_ROWS * H2_DIM;           // 4194304
    const size_t smallN = (size_t)M_BOOKS*N_ROWS + (size_t)M_BOOKS*K_CODES
                        + 2 + 2*(size_t)M_BOOKS*N_ROWS;
    const size_t fullFloats = (size_t)M_BOOKS*(h1N1 + h2N1) + smallN;
    const bool fullM = ws_size >= fullFloats * sizeof(float) + 256;

    size_t off = 0;
    float* h1 = ws; off += (fullM ? M_BOOKS : 1) * h1N1;
    float* h2 = ws + off; off += (fullM ? M_BOOKS : 1) * h2N1;
    float* zesq = ws + off; off += (size_t)M_BOOKS * N_ROWS;
    float* cbsq = ws + off; off += (size_t)M_BOOKS * K_CODES;
    off = (off + 1) & ~(size_t)1;
    unsigned long long* keys = (unsigned long long*)(ws + off);
    float* zq = h1;   // reuse after encoders finish
    float* d1 = h2;
    float* d2 = h1;   // zq dead once decoder L1 done

    hipMemsetAsync((void*)keys, 0xFF, (size_t)M_BOOKS * N_ROWS * 8, stream);

    dim3 blk(256, 1, 1);
    const int nz = fullM ? M_BOOKS : 1;
    const int nloop = fullM ? 1 : M_BOOKS;
    for (int p = 0; p < nloop; ++p) {
        const size_t mb = fullM ? 0 : (size_t)p;
        // encoder L1: x[N,E] @ W1[E,H1] + BN + ReLU
        gemm128<32, true><<<dim3(H1_DIM/128, N_ROWS/128, nz), blk, 0, stream>>>(
            x, eW1 + mb * (size_t)E_DIM * H1_DIM,
            eb1 + mb*H1_DIM, g1 + mb*H1_DIM, b1 + mb*H1_DIM, m1 + mb*H1_DIM, v1 + mb*H1_DIM,
            h1, E_DIM, H1_DIM,
            0, (size_t)E_DIM * H1_DIM, H1_DIM, h1N1);
        // encoder L2: h1 @ W2[H1,H2] + BN + ReLU
        gemm128<32, true><<<dim3(H2_DIM/128, N_ROWS/128, nz), blk, 0, stream>>>(
            h1, eW2 + mb * (size_t)H1_DIM * H2_DIM,
            eb2 + mb*H2_DIM, g2 + mb*H2_DIM, b2 + mb*H2_DIM, m2 + mb*H2_DIM, v2 + mb*H2_DIM,
            h2, H1_DIM, H2_DIM,
            h1N1, (size_t)H1_DIM * H2_DIM, H2_DIM, h2N1);
        // encoder L3: h2 @ W3[H2,C] + bias -> ze straight into d_out (fp32)
        gemm128<32, false><<<dim3(C_DIM/128, N_ROWS/128, nz), blk, 0, stream>>>(
            h2, eW3 + mb * (size_t)H2_DIM * C_DIM,
            eb3 + mb*C_DIM, nullptr, nullptr, nullptr, nullptr,
            out_ze + mb * (size_t)N_ROWS * C_DIM, H2_DIM, C_DIM,
            h2N1, (size_t)H2_DIM * C_DIM, C_DIM, (size_t)N_ROWS * C_DIM);
    }

    rowsq_np<<<dim3((M_BOOKS * N_ROWS) / 256), blk, 0, stream>>>(out_ze, zesq, M_BOOKS * N_ROWS);
    rowsq_np<<<dim3((M_BOOKS * K_CODES) / 256), blk, 0, stream>>>(cb, cbsq, M_BOOKS * K_CODES);
    vq_argmin<<<dim3(K_CODES/128, N_ROWS/128, M_BOOKS), blk, 0, stream>>>(
        out_ze, cb, zesq, cbsq, keys);
    gather_ce_zq<<<dim3((N_ROWS * C_DIM) / 256), blk, 0, stream>>>(keys, cb, out_ce, zq);

    // decoder
    gemm128<32, true><<<dim3(H2_DIM/128, N_ROWS/128, 1), blk, 0, stream>>>(
        zq, dW1, db1, dg1, dbb1, dm1, dv1, d1, C_DIM, H2_DIM, 0, 0, 0, 0);
    gemm128<32, true><<<dim3(H1_DIM/128, N_ROWS/128, 1), blk, 0, stream>>>(
        d1, dW2, db2, dg2, dbb2, dm2, dv2, d2, H2_DIM, H1_DIM, 0, 0, 0, 0);
    gemm128<32, false><<<dim3(E_DIM/128, N_ROWS/128, 1), blk, 0, stream>>>(
        d2, dW3, db3, nullptr, nullptr, nullptr, nullptr,
        out_xhat, H1_DIM, E_DIM, 0, 0, 0, 0);
}